// Round 9
// baseline (1047.958 us; speedup 1.0000x reference)
//
#include <hip/hip_runtime.h>
#include <hip/hip_bf16.h>

#define Sn    2048
#define HIDn  2048
#define HQn   16
#define HKVn  2
#define HDn   128
#define Gn    8
#define CSn   128
#define Ncn   16
#define NBLK  8
#define WINn  16
#define SCALEf 0.08838834764831845f   // 128^-0.5
#define NEGf  (-1.0e9f)
#define ALPHAf 0.8f
#define MIXLf  0.5f
#define EPSGAP 2.0e-3f
#define FLAGCAP 2040

typedef __attribute__((ext_vector_type(8))) short short8;   // 8 bf16 = 4 VGPRs
typedef __attribute__((ext_vector_type(4))) float f32x4;

static __device__ __forceinline__ short f2bf(float x) {
    union { float f; unsigned u; } v; v.f = x;
    unsigned r = v.u + 0x7fffu + ((v.u >> 16) & 1u);
    return (short)(r >> 16);
}
static __device__ __forceinline__ float bf2f(short b) {
    union { float f; unsigned u; } v; v.u = ((unsigned)(unsigned short)b) << 16;
    return v.f;
}

// ---------------- fp32 GEMM (K proj + fallback path) ----------------
__global__ void gemm64(const float* __restrict__ A, const float* __restrict__ W,
                       const float* __restrict__ bias, float* __restrict__ C,
                       int M, int N, int K) {
    __shared__ float As[16][65];
    __shared__ float Bs[16][65];
    const int tid = threadIdx.x;
    const int tx = tid & 15, ty = tid >> 4;
    const int m0 = blockIdx.y * 64, n0 = blockIdx.x * 64;
    float acc[4][4] = {};
    for (int k0 = 0; k0 < K; k0 += 16) {
#pragma unroll
        for (int r = 0; r < 4; ++r) {
            int flat = tid + 256 * r;
            int am = flat >> 4, ak = flat & 15;
            As[ak][am] = A[(size_t)(m0 + am) * K + k0 + ak];
            int bk = flat >> 6, bn = flat & 63;
            Bs[bk][bn] = W[(size_t)(k0 + bk) * N + n0 + bn];
        }
        __syncthreads();
#pragma unroll
        for (int kk = 0; kk < 16; ++kk) {
            float a[4], b[4];
#pragma unroll
            for (int i = 0; i < 4; ++i) a[i] = As[kk][ty * 4 + i];
#pragma unroll
            for (int j = 0; j < 4; ++j) b[j] = Bs[kk][tx * 4 + j];
#pragma unroll
            for (int i = 0; i < 4; ++i)
#pragma unroll
                for (int j = 0; j < 4; ++j) acc[i][j] += a[i] * b[j];
        }
        __syncthreads();
    }
#pragma unroll
    for (int i = 0; i < 4; ++i)
#pragma unroll
        for (int j = 0; j < 4; ++j) {
            int m = m0 + ty * 4 + i, n = n0 + tx * 4 + j;
            C[(size_t)m * N + n] = acc[i][j] + (bias ? bias[n] : 0.0f);
        }
}

// ---------------- W[K][N] fp32 -> Wt[N][K] bf16 hi (+lo) ----------------
__global__ void trans_split(const float* __restrict__ W, short* __restrict__ Whi,
                            short* __restrict__ Wlo, int K, int N) {
    __shared__ float tl[32][33];
    const int k0 = blockIdx.y * 32, n0 = blockIdx.x * 32;
    const int c = threadIdx.x & 31, r8 = threadIdx.x >> 5;
#pragma unroll
    for (int it = 0; it < 4; ++it) {
        int r = r8 + it * 8;
        tl[r][c] = W[(size_t)(k0 + r) * N + n0 + c];
    }
    __syncthreads();
#pragma unroll
    for (int it = 0; it < 4; ++it) {
        int r = r8 + it * 8;
        float x = tl[c][r];                      // = W[k0+c][n0+r]
        short hi = f2bf(x);
        Whi[(size_t)(n0 + r) * K + k0 + c] = hi;
        if (Wlo) Wlo[(size_t)(n0 + r) * K + k0 + c] = f2bf(x - bf2f(hi));
    }
}

// ---------------- MFMA GEMM: C[M,N] = A[M,K] @ B + bias ----------------
// B transposed bf16 [N][K]. AMODE: 0 = A bf16; 1 = A fp32 split bf16x3;
// 2 = A fp32 rounded to bf16 (single). VOUT: epilogue writes vtb bf16
// [kv][c][d][j] (V-projection fused with the chunk-transpose).
template <int AMODE, bool VOUT>
__global__ __launch_bounds__(256) void gemm_mfma(
        const void* __restrict__ Av, const short* __restrict__ Bhi,
        const short* __restrict__ Blo, const float* __restrict__ bias,
        float* __restrict__ C, short* __restrict__ vout, int M, int N, int K) {
    __shared__ short Ahs[128][40];
    __shared__ short Bhs[128][40];
    __shared__ short Als[AMODE == 1 ? 128 : 1][40];
    __shared__ short Bls[AMODE == 1 ? 128 : 1][40];
    const int tid = threadIdx.x;
    const int w = tid >> 6, lane = tid & 63, nl = lane & 15, quad = lane >> 4;
    const int wm = w >> 1, wn = w & 1;
    const int m0 = blockIdx.y * 128, n0 = blockIdx.x * 128;
    const int srow = tid >> 1, sseg = tid & 1;
    f32x4 acc[4][4];
#pragma unroll
    for (int i = 0; i < 4; ++i)
#pragma unroll
        for (int j = 0; j < 4; ++j) acc[i][j] = (f32x4){0.f, 0.f, 0.f, 0.f};

    for (int k0 = 0; k0 < K; k0 += 32) {
        if (AMODE != 0) {
            const float* A = (const float*)Av;
            const float* ap = A + (size_t)(m0 + srow) * K + k0 + sseg * 16;
            short8 hi0, hi1, lo0, lo1;
#pragma unroll
            for (int i = 0; i < 8; ++i) {
                float x = ap[i];
                short h = f2bf(x);
                hi0[i] = h; if (AMODE == 1) lo0[i] = f2bf(x - bf2f(h));
            }
#pragma unroll
            for (int i = 0; i < 8; ++i) {
                float x = ap[8 + i];
                short h = f2bf(x);
                hi1[i] = h; if (AMODE == 1) lo1[i] = f2bf(x - bf2f(h));
            }
            *(short8*)&Ahs[srow][sseg * 16] = hi0;
            *(short8*)&Ahs[srow][sseg * 16 + 8] = hi1;
            if (AMODE == 1) {
                *(short8*)&Als[srow][sseg * 16] = lo0;
                *(short8*)&Als[srow][sseg * 16 + 8] = lo1;
            }
        } else {
            const short* A = (const short*)Av;
            const short* ap = A + (size_t)(m0 + srow) * K + k0 + sseg * 16;
            *(short8*)&Ahs[srow][sseg * 16]     = *(const short8*)(ap);
            *(short8*)&Ahs[srow][sseg * 16 + 8] = *(const short8*)(ap + 8);
        }
        {
            const short* bh = Bhi + (size_t)(n0 + srow) * K + k0 + sseg * 16;
            *(short8*)&Bhs[srow][sseg * 16]     = *(const short8*)(bh);
            *(short8*)&Bhs[srow][sseg * 16 + 8] = *(const short8*)(bh + 8);
        }
        if (AMODE == 1) {
            const short* bl = Blo + (size_t)(n0 + srow) * K + k0 + sseg * 16;
            *(short8*)&Bls[srow][sseg * 16]     = *(const short8*)(bl);
            *(short8*)&Bls[srow][sseg * 16 + 8] = *(const short8*)(bl + 8);
        }
        __syncthreads();
        short8 af[4], bf_[4], al[4], bl_[4];
#pragma unroll
        for (int tm = 0; tm < 4; ++tm)
            af[tm] = *(const short8*)&Ahs[wm * 64 + tm * 16 + nl][quad * 8];
#pragma unroll
        for (int tn = 0; tn < 4; ++tn)
            bf_[tn] = *(const short8*)&Bhs[wn * 64 + tn * 16 + nl][quad * 8];
        if (AMODE == 1) {
#pragma unroll
            for (int tm = 0; tm < 4; ++tm)
                al[tm] = *(const short8*)&Als[wm * 64 + tm * 16 + nl][quad * 8];
#pragma unroll
            for (int tn = 0; tn < 4; ++tn)
                bl_[tn] = *(const short8*)&Bls[wn * 64 + tn * 16 + nl][quad * 8];
        }
#pragma unroll
        for (int tm = 0; tm < 4; ++tm)
#pragma unroll
            for (int tn = 0; tn < 4; ++tn) {
                acc[tm][tn] = __builtin_amdgcn_mfma_f32_16x16x32_bf16(af[tm], bf_[tn], acc[tm][tn], 0, 0, 0);
                if (AMODE == 1) {
                    acc[tm][tn] = __builtin_amdgcn_mfma_f32_16x16x32_bf16(af[tm], bl_[tn], acc[tm][tn], 0, 0, 0);
                    acc[tm][tn] = __builtin_amdgcn_mfma_f32_16x16x32_bf16(al[tm], bf_[tn], acc[tm][tn], 0, 0, 0);
                }
            }
        __syncthreads();
    }
#pragma unroll
    for (int tm = 0; tm < 4; ++tm)
#pragma unroll
        for (int tn = 0; tn < 4; ++tn)
#pragma unroll
            for (int r = 0; r < 4; ++r) {
                int m = m0 + wm * 64 + tm * 16 + quad * 4 + r;
                int n = n0 + wn * 64 + tn * 16 + nl;
                float v = acc[tm][tn][r] + (bias ? bias[n] : 0.0f);
                if (VOUT) {
                    int kv = n >> 7, d = n & 127, cc = m >> 7, j = m & 127;
                    vout[(((size_t)kv * Ncn + cc) * 128 + d) * 128 + j] = f2bf(v);
                } else {
                    C[(size_t)m * N + n] = v;
                }
            }
}

// ---------------- RoPE in-place on q and k; k also -> bf16 ----------------
__global__ void rope_kernel(float* __restrict__ q, float* __restrict__ k,
                            const float* __restrict__ cosb, const float* __restrict__ sinb,
                            short* __restrict__ kb) {
    int idx = blockIdx.x * blockDim.x + threadIdx.x;   // S*18*64
    int s = idx / (18 * 64);
    int r = idx % (18 * 64);
    int head = r >> 6;
    int d = r & 63;
    float c0 = cosb[s * 128 + d], c1 = cosb[s * 128 + d + 64];
    float s0 = sinb[s * 128 + d], s1 = sinb[s * 128 + d + 64];
    if (head < 16) {
        float* base = q + (size_t)s * 2048 + head * 128;
        float x0 = base[d], x1 = base[d + 64];
        base[d]      = x0 * c0 - x1 * s0;
        base[d + 64] = x1 * c1 + x0 * s1;
    } else {
        int kv = head - 16;
        float* base = k + (size_t)s * 256 + kv * 128;
        float x0 = base[d], x1 = base[d + 64];
        float y0 = x0 * c0 - x1 * s0;
        float y1 = x1 * c1 + x0 * s1;
        base[d] = y0; base[d + 64] = y1;
        short* ko = kb + ((size_t)kv * Sn + s) * 128;
        ko[d] = f2bf(y0); ko[d + 64] = f2bf(y1);
    }
}

// ---------------- V -> bf16, transposed per chunk (fallback path only) ----------
__global__ void conv_v(const float* __restrict__ v, short* __restrict__ vtb) {
    int idx = blockIdx.x * blockDim.x + threadIdx.x;   // S*256
    int pos = idx >> 8;
    int rem = idx & 255;
    int kv = rem >> 7, d = rem & 127;
    float val = v[(size_t)pos * 256 + kv * 128 + d];
    int c = pos >> 7, j = pos & 127;
    vtb[(((size_t)kv * Ncn + c) * 128 + d) * 128 + j] = f2bf(val);
}

// ---------------- per-chunk K stats (+ zero the tie-flag counter) ----------------
__global__ void chunk_stats(const float* __restrict__ k, float* __restrict__ kcm,
                            float* __restrict__ kcx, int* __restrict__ flags) {
    if (blockIdx.x == 0 && threadIdx.x == 0) flags[0] = 0;
    int c = blockIdx.x & 15, kv = blockIdx.x >> 4;
    int d = threadIdx.x;
    float sum = 0.f, mx = -INFINITY;
    for (int j = 0; j < 128; ++j) {
        float v = k[(size_t)(c * 128 + j) * 256 + kv * 128 + d];
        sum += v; mx = fmaxf(mx, v);
    }
    kcm[(kv * 16 + c) * 128 + d] = sum * (1.0f / 128.0f);
    kcx[(kv * 16 + c) * 128 + d] = mx;
}

// ---------------- block scores + top-8 -> chunk mask; flag genuine near-ties ----
__global__ void block_scores(const float* __restrict__ q, const float* __restrict__ kcm,
                             const float* __restrict__ kcx, unsigned int* __restrict__ mask32,
                             int* __restrict__ flags) {
    int qpos = blockIdx.x, kv = blockIdx.y;
    int t = threadIdx.x;          // 128: t = c*8 + g
    int c = t >> 3, g = t & 7;
    int h = kv * 8 + g;
    const float* qr = q + (size_t)qpos * 2048 + h * 128;
    const float* km = kcm + (kv * 16 + c) * 128;
    const float* kx = kcx + (kv * 16 + c) * 128;
    float dm = 0.f, dx = 0.f;
#pragma unroll 4
    for (int d = 0; d < 128; ++d) { float qv = qr[d]; dm += qv * km[d]; dx += qv * kx[d]; }
    float sg = (MIXLf * dm + (1.0f - MIXLf) * dx) * SCALEf;
    __shared__ float sh[16][8];
    __shared__ float vals[16];
    sh[c][g] = sg;
    __syncthreads();
    if (t < 16) {
        float mean = 0.f, mxv = -INFINITY;
#pragma unroll
        for (int gg = 0; gg < 8; ++gg) { mean += sh[t][gg]; mxv = fmaxf(mxv, sh[t][gg]); }
        mean *= 0.125f;
        float v = ALPHAf * mean + (1.0f - ALPHAf) * mxv;
        if (t * 128 > qpos) v = NEGf;
        vals[t] = v;
    }
    __syncthreads();
    if (t == 0) {
        unsigned int bits = 0;
        bool taken[16] = {};
        float v8 = -INFINITY;
        for (int it = 0; it < NBLK; ++it) {
            int best = 0; float bv = -INFINITY;
            for (int cc = 0; cc < 16; ++cc)
                if (!taken[cc] && vals[cc] > bv) { bv = vals[cc]; best = cc; }
            taken[best] = true;
            bits |= (1u << best);
            v8 = bv;
        }
        float v9 = -INFINITY;
        for (int cc = 0; cc < 16; ++cc)
            if (!taken[cc] && vals[cc] > v9) v9 = vals[cc];
        int lastc = qpos >> 7;
        unsigned int causal_bits = (1u << (lastc + 1)) - 1u;
        mask32[kv * 2048 + qpos] = bits & causal_bits;
        if (v9 > -0.5e9f && v8 - v9 < EPSGAP) {
            int idx = atomicAdd(flags, 1);
            if (idx < FLAGCAP) flags[1 + idx] = (kv << 16) | qpos;
        }
    }
}

// ---------------- exact fp32 q for flagged rows (parallel) ----------------
__global__ __launch_bounds__(256) void fixup_q(
        const float* __restrict__ hs, const float* __restrict__ Wq,
        const float* __restrict__ bq, const float* __restrict__ cosb,
        const float* __restrict__ sinb, const int* __restrict__ flags,
        float* __restrict__ qfix) {
    int cnt = flags[0]; if (cnt > FLAGCAP) cnt = FLAGCAP;
    const int items = cnt * 8;
    const int tid = threadIdx.x;
    __shared__ float hssh[2048];
    __shared__ float part[2][128];
    __shared__ float qrow[128];
    for (int item = blockIdx.x; item < items; item += gridDim.x) {
        int i = item >> 3, g = item & 7;
        int e = flags[1 + i];
        int kv = e >> 16, qpos = e & 0xffff;
        for (int j = tid; j < 2048; j += 256) hssh[j] = hs[(size_t)qpos * 2048 + j];
        __syncthreads();
        int d = tid & 127, half = tid >> 7;
        int col = (kv * 8 + g) * 128 + d;
        float s0 = 0.f, s1 = 0.f, s2 = 0.f, s3 = 0.f;
        const float* wp = Wq + (size_t)(half * 1024) * 2048 + col;
        const float* hp = hssh + half * 1024;
        for (int k = 0; k < 1024; k += 4) {
            s0 += hp[k + 0] * wp[(size_t)(k + 0) * 2048];
            s1 += hp[k + 1] * wp[(size_t)(k + 1) * 2048];
            s2 += hp[k + 2] * wp[(size_t)(k + 2) * 2048];
            s3 += hp[k + 3] * wp[(size_t)(k + 3) * 2048];
        }
        part[half][d] = (s0 + s1) + (s2 + s3);
        __syncthreads();
        if (tid < 128) qrow[tid] = part[0][tid] + part[1][tid] + bq[col];
        __syncthreads();
        if (tid < 64) {
            int dd = tid;
            float c0 = cosb[qpos * 128 + dd], c1 = cosb[qpos * 128 + dd + 64];
            float s0_ = sinb[qpos * 128 + dd], s1_ = sinb[qpos * 128 + dd + 64];
            float x0 = qrow[dd], x1 = qrow[dd + 64];
            qfix[(size_t)i * 1024 + g * 128 + dd]      = x0 * c0 - x1 * s0_;
            qfix[(size_t)i * 1024 + g * 128 + dd + 64] = x1 * c1 + x0 * s1_;
        }
        __syncthreads();
    }
}

// ---------------- redo top-8 for flagged rows from exact q ----------------
__global__ void fixup_sel(const float* __restrict__ qfix, const float* __restrict__ kcm,
                          const float* __restrict__ kcx, const int* __restrict__ flags,
                          unsigned int* __restrict__ mask32) {
    int cnt = flags[0]; if (cnt > FLAGCAP) cnt = FLAGCAP;
    int i = blockIdx.x;
    if (i >= cnt) return;
    int e = flags[1 + i];
    int kv = e >> 16, qpos = e & 0xffff;
    int t = threadIdx.x;
    int c = t >> 3, g = t & 7;
    const float* qr = qfix + (size_t)i * 1024 + g * 128;
    const float* km = kcm + (kv * 16 + c) * 128;
    const float* kx = kcx + (kv * 16 + c) * 128;
    float dm = 0.f, dx = 0.f;
#pragma unroll 4
    for (int d = 0; d < 128; ++d) { float qv = qr[d]; dm += qv * km[d]; dx += qv * kx[d]; }
    float sg = (MIXLf * dm + (1.0f - MIXLf) * dx) * SCALEf;
    __shared__ float sh[16][8];
    __shared__ float vals[16];
    sh[c][g] = sg;
    __syncthreads();
    if (t < 16) {
        float mean = 0.f, mxv = -INFINITY;
#pragma unroll
        for (int gg = 0; gg < 8; ++gg) { mean += sh[t][gg]; mxv = fmaxf(mxv, sh[t][gg]); }
        mean *= 0.125f;
        float v = ALPHAf * mean + (1.0f - ALPHAf) * mxv;
        if (t * 128 > qpos) v = NEGf;
        vals[t] = v;
    }
    __syncthreads();
    if (t == 0) {
        unsigned int bits = 0;
        bool taken[16] = {};
        for (int it = 0; it < NBLK; ++it) {
            int best = 0; float bv = -INFINITY;
            for (int cc = 0; cc < 16; ++cc)
                if (!taken[cc] && vals[cc] > bv) { bv = vals[cc]; best = cc; }
            taken[best] = true;
            bits |= (1u << best);
        }
        int lastc = qpos >> 7;
        unsigned int causal_bits = (1u << (lastc + 1)) - 1u;
        mask32[kv * 2048 + qpos] = bits & causal_bits;
    }
}

// ---------------- MFMA flash attention (chunk-split across 4 waves + merge) ----
// Block = (16-row strip, head). The strip's chunk list is dealt round-robin to
// the 4 waves; each computes a partial (m,l,O); merged via exp(m-M) scaling in
// LDS (exactly the online-softmax algebra, so NEG-garbage partials scale to 0).
__global__ __launch_bounds__(256, 4) void attn_mfma(
        float* __restrict__ qbuf, const short* __restrict__ kb,
        const short* __restrict__ vtb, const unsigned int* __restrict__ mask32,
        const int* __restrict__ am, short* __restrict__ ab) {
    __shared__ short Psh[4][16][136];
    __shared__ float Mb[4][16];
    __shared__ float Lb[4][16];
    __shared__ float Ob[8][16][17];   // [dt][row][col+pad] merged O
    const int tid = threadIdx.x;
    const int w = tid >> 6, lane = tid & 63;
    const int nl = lane & 15, quad = lane >> 4;
    const int h = blockIdx.y, kv = h >> 3;
    const int r0 = blockIdx.x * 16;

    for (int i = tid; i < 8 * 16 * 17; i += 256) ((float*)Ob)[i] = 0.f;

    int qpos[4];
    unsigned rb[4];
#pragma unroll
    for (int r = 0; r < 4; ++r) {
        qpos[r] = r0 + quad * 4 + r;
        rb[r] = mask32[kv * Sn + qpos[r]];
    }
    unsigned bits = mask32[kv * Sn + r0 + nl];
#pragma unroll
    for (int off = 1; off < 64; off <<= 1) bits |= __shfl_xor(bits, off, 64);
    int wl = (r0 >= 15) ? ((r0 - 15) >> 7) : 0;
    int wh = (r0 + 15) >> 7;
    for (int c = wl; c <= wh; ++c) bits |= (1u << c);
    const int cm = (r0 + 15) >> 7;
    bits &= (1u << (cm + 1)) - 1u;

    short8 qf[4];
    const float* qrow = qbuf + (size_t)(r0 + nl) * 2048 + h * 128;
#pragma unroll
    for (int ks = 0; ks < 4; ++ks) {
        float4 a = *(const float4*)(qrow + ks * 32 + quad * 8);
        float4 b = *(const float4*)(qrow + ks * 32 + quad * 8 + 4);
        short8 v;
        v[0] = f2bf(a.x); v[1] = f2bf(a.y); v[2] = f2bf(a.z); v[3] = f2bf(a.w);
        v[4] = f2bf(b.x); v[5] = f2bf(b.y); v[6] = f2bf(b.z); v[7] = f2bf(b.w);
        qf[ks] = v;
    }

    f32x4 oacc[8];
#pragma unroll
    for (int dt = 0; dt < 8; ++dt) oacc[dt] = (f32x4){0.f, 0.f, 0.f, 0.f};
    float m[4] = {-INFINITY, -INFINITY, -INFINITY, -INFINITY};
    float l[4] = {0.f, 0.f, 0.f, 0.f};

    unsigned remb = bits;
    int ci = 0;
    while (remb) {
        const int c = __builtin_ctz(remb);
        remb &= remb - 1;
        if (((ci++) & 3) != w) continue;     // round-robin chunk assignment
        const short* kcbase = kb + ((size_t)kv * Sn + c * 128) * 128;
        f32x4 sacc[8];
#pragma unroll
        for (int t = 0; t < 8; ++t) {
            const short* krow = kcbase + (t * 16 + nl) * 128;
            f32x4 a = (f32x4){0.f, 0.f, 0.f, 0.f};
#pragma unroll
            for (int ks = 0; ks < 4; ++ks) {
                short8 kf = *(const short8*)(krow + ks * 32 + quad * 8);
                a = __builtin_amdgcn_mfma_f32_16x16x32_bf16(qf[ks], kf, a, 0, 0, 0);
            }
            sacc[t] = a;
        }
        float cmax[4] = {-INFINITY, -INFINITY, -INFINITY, -INFINITY};
#pragma unroll
        for (int t = 0; t < 8; ++t) {
            int kp = c * 128 + t * 16 + nl;
            bool amok = am[kp] != 0;
#pragma unroll
            for (int r = 0; r < 4; ++r) {
                float s = sacc[t][r] * SCALEf;
                bool ok = (kp <= qpos[r]) && amok &&
                          (((rb[r] >> c) & 1u) || (qpos[r] - kp) < WINn);
                s = ok ? s : NEGf;
                sacc[t][r] = s;
                cmax[r] = fmaxf(cmax[r], s);
            }
        }
#pragma unroll
        for (int r = 0; r < 4; ++r)
#pragma unroll
            for (int off = 1; off < 16; off <<= 1)
                cmax[r] = fmaxf(cmax[r], __shfl_xor(cmax[r], off, 64));
        float fac[4], rsum[4];
#pragma unroll
        for (int r = 0; r < 4; ++r) {
            float newm = fmaxf(m[r], cmax[r]);
            fac[r] = __expf(m[r] - newm);
            m[r] = newm;
            rsum[r] = 0.f;
        }
#pragma unroll
        for (int t = 0; t < 8; ++t)
#pragma unroll
            for (int r = 0; r < 4; ++r) {
                float p = __expf(sacc[t][r] - m[r]);
                rsum[r] += p;
                Psh[w][quad * 4 + r][t * 16 + nl] = f2bf(p);
            }
#pragma unroll
        for (int r = 0; r < 4; ++r) {
#pragma unroll
            for (int off = 1; off < 16; off <<= 1)
                rsum[r] += __shfl_xor(rsum[r], off, 64);
            l[r] = l[r] * fac[r] + rsum[r];
        }
#pragma unroll
        for (int dt = 0; dt < 8; ++dt)
#pragma unroll
            for (int r = 0; r < 4; ++r) oacc[dt][r] *= fac[r];
        short8 pf[4];
        const short* prow = &Psh[w][nl][0];
#pragma unroll
        for (int ks = 0; ks < 4; ++ks) pf[ks] = *(const short8*)(prow + ks * 32 + quad * 8);
        const short* vcbase = vtb + (((size_t)kv * Ncn + c) * 128) * 128;
#pragma unroll
        for (int dt = 0; dt < 8; ++dt) {
            const short* vrow = vcbase + (dt * 16 + nl) * 128;
#pragma unroll
            for (int ks = 0; ks < 4; ++ks) {
                short8 vf = *(const short8*)(vrow + ks * 32 + quad * 8);
                oacc[dt] = __builtin_amdgcn_mfma_f32_16x16x32_bf16(pf[ks], vf, oacc[dt], 0, 0, 0);
            }
        }
    }
    // ---- merge the 4 partials ----
    if (nl == 0) {
#pragma unroll
        for (int r = 0; r < 4; ++r) Mb[w][quad * 4 + r] = m[r];
    }
    __syncthreads();
    float scale[4];
#pragma unroll
    for (int r = 0; r < 4; ++r) {
        int row = quad * 4 + r;
        float M = fmaxf(fmaxf(Mb[0][row], Mb[1][row]), fmaxf(Mb[2][row], Mb[3][row]));
        scale[r] = __expf(m[r] - M);        // empty/garbage partial -> 0
    }
    if (nl == 0) {
#pragma unroll
        for (int r = 0; r < 4; ++r) Lb[w][quad * 4 + r] = l[r] * scale[r];
    }
#pragma unroll
    for (int dt = 0; dt < 8; ++dt)
#pragma unroll
        for (int r = 0; r < 4; ++r)
            atomicAdd(&Ob[dt][quad * 4 + r][nl], oacc[dt][r] * scale[r]);
    __syncthreads();
#pragma unroll
    for (int j = 0; j < 2; ++j) {
        int dt = w + j * 4;
#pragma unroll
        for (int r = 0; r < 4; ++r) {
            int row = quad * 4 + r;
            float L = (Lb[0][row] + Lb[1][row]) + (Lb[2][row] + Lb[3][row]);
            float val = Ob[dt][row][nl] / L;
            size_t off = (size_t)(r0 + row) * 2048 + h * 128 + dt * 16 + nl;
            qbuf[off] = val;
            ab[off] = f2bf(val);
        }
    }
}

extern "C" void kernel_launch(void* const* d_in, const int* in_sizes, int n_in,
                              void* d_out, int out_size, void* d_ws, size_t ws_size,
                              hipStream_t stream) {
    const float* hs   = (const float*)d_in[0];
    const float* cosb = (const float*)d_in[1];
    const float* sinb = (const float*)d_in[2];
    const int*   am   = (const int*)d_in[3];
    const float* Wq = (const float*)d_in[5];
    const float* bq = (const float*)d_in[6];
    const float* Wk = (const float*)d_in[7];
    const float* bk = (const float*)d_in[8];
    const float* Wv = (const float*)d_in[9];
    const float* bv = (const float*)d_in[10];
    const float* Wo = (const float*)d_in[11];
    float* out = (float*)d_out;

    float* qbuf = (float*)d_ws;                       // 4,194,304 f
    float* kbuf = qbuf + (size_t)Sn * HIDn;           // 524,288 f
    float* vbuf = kbuf + (size_t)Sn * HKVn * HDn;     // 524,288 f (fallback V / big-path WvT)
    float* kcm  = vbuf + (size_t)Sn * HKVn * HDn;     // 4096 f
    float* kcx  = kcm + 4096;                         // 4096 f
    unsigned int* mask32 = (unsigned int*)(kcx + 4096);  // 4096 u32
    int* flags = (int*)(mask32 + 4096);               // 4096 i32
    short* kb  = (short*)(flags + 4096);              // 524,288 s
    short* vtb = kb + (size_t)HKVn * Sn * HDn;        // 524,288 s
    char* P = (char*)(vtb + (size_t)HKVn * Sn * HDn);
    const size_t WSZ = (size_t)HIDn * HIDn * sizeof(short);   // 8,388,608 B
    size_t base = (size_t)((char*)P - (char*)d_ws);
    bool big = ws_size >= base + 2 * WSZ;

    dim3 blk(256);
    if (big) {
        short* W1 = (short*)P;              // Wq hi^T; later qfix; later Wo^T
        short* W2 = (short*)(P + WSZ);      // Wq lo^T; later ab
        short* ab = W2;
        float* qfix = (float*)W1;
        short* WvT = (short*)vbuf;          // 256*2048 s = 1 MB (vbuf unused on big path)
        trans_split<<<dim3(64, 64), blk, 0, stream>>>(Wq, W1, W2, HIDn, HIDn);
        gemm_mfma<1, false><<<dim3(16, 16), blk, 0, stream>>>(hs, W1, W2, bq, qbuf, nullptr, Sn, HIDn, HIDn);
        gemm64<<<dim3((HKVn * HDn) / 64, Sn / 64), blk, 0, stream>>>(hs, Wk, bk, kbuf, Sn, HKVn * HDn, HIDn);
        trans_split<<<dim3(8, 64), blk, 0, stream>>>(Wv, WvT, nullptr, HIDn, HKVn * HDn);
        gemm_mfma<2, true><<<dim3(2, 16), blk, 0, stream>>>(hs, WvT, nullptr, bv, nullptr, vtb, Sn, HKVn * HDn, HIDn);
        rope_kernel<<<(Sn * 18 * 64) / 256, blk, 0, stream>>>(qbuf, kbuf, cosb, sinb, kb);
        chunk_stats<<<HKVn * Ncn, 128, 0, stream>>>(kbuf, kcm, kcx, flags);
        block_scores<<<dim3(Sn, HKVn), 128, 0, stream>>>(qbuf, kcm, kcx, mask32, flags);
        fixup_q<<<2048, blk, 0, stream>>>(hs, Wq, bq, cosb, sinb, flags, qfix);
        fixup_sel<<<FLAGCAP, 128, 0, stream>>>(qfix, kcm, kcx, flags, mask32);
        attn_mfma<<<dim3(Sn / 16, HQn), blk, 0, stream>>>(qbuf, kb, vtb, mask32, am, ab);
        trans_split<<<dim3(64, 64), blk, 0, stream>>>(Wo, W1, nullptr, HIDn, HIDn);
        gemm_mfma<0, false><<<dim3(16, 16), blk, 0, stream>>>(ab, W1, nullptr, nullptr, out, nullptr, Sn, HIDn, HIDn);
    } else {
        short* ab = (short*)P;
        gemm64<<<dim3(HIDn / 64, Sn / 64), blk, 0, stream>>>(hs, Wq, bq, qbuf, Sn, HIDn, HIDn);
        gemm64<<<dim3((HKVn * HDn) / 64, Sn / 64), blk, 0, stream>>>(hs, Wk, bk, kbuf, Sn, HKVn * HDn, HIDn);
        gemm64<<<dim3((HKVn * HDn) / 64, Sn / 64), blk, 0, stream>>>(hs, Wv, bv, vbuf, Sn, HKVn * HDn, HIDn);
        rope_kernel<<<(Sn * 18 * 64) / 256, blk, 0, stream>>>(qbuf, kbuf, cosb, sinb, kb);
        conv_v<<<(Sn * 256) / 256, blk, 0, stream>>>(vbuf, vtb);
        chunk_stats<<<HKVn * Ncn, 128, 0, stream>>>(kbuf, kcm, kcx, flags);
        block_scores<<<dim3(Sn, HKVn), 128, 0, stream>>>(qbuf, kcm, kcx, mask32, flags);
        attn_mfma<<<dim3(Sn / 16, HQn), blk, 0, stream>>>(qbuf, kb, vtb, mask32, am, ab);
        gemm64<<<dim3(HIDn / 64, Sn / 64), blk, 0, stream>>>(qbuf, Wo, nullptr, out, Sn, HIDn, HIDn);
    }
}

// Round 10
// 1033.398 us; speedup vs baseline: 1.0141x; 1.0141x over previous
//
#include <hip/hip_runtime.h>
#include <hip/hip_bf16.h>

#define Sn    2048
#define HIDn  2048
#define HQn   16
#define HKVn  2
#define HDn   128
#define Gn    8
#define CSn   128
#define Ncn   16
#define NBLK  8
#define WINn  16
#define SCALEf 0.08838834764831845f   // 128^-0.5
#define NEGf  (-1.0e9f)
#define ALPHAf 0.8f
#define MIXLf  0.5f
#define EPSGAP 2.0e-3f
#define FLAGCAP 2040
#define KROW  130                      // LDS row stride (shorts): 128 + 2 pad

typedef __attribute__((ext_vector_type(8))) short short8;   // 8 bf16 = 4 VGPRs
typedef __attribute__((ext_vector_type(4))) float f32x4;

static __device__ __forceinline__ short f2bf(float x) {
    union { float f; unsigned u; } v; v.f = x;
    unsigned r = v.u + 0x7fffu + ((v.u >> 16) & 1u);
    return (short)(r >> 16);
}
static __device__ __forceinline__ float bf2f(short b) {
    union { float f; unsigned u; } v; v.u = ((unsigned)(unsigned short)b) << 16;
    return v.f;
}

// ---------------- fp32 GEMM (K proj + fallback path) ----------------
__global__ void gemm64(const float* __restrict__ A, const float* __restrict__ W,
                       const float* __restrict__ bias, float* __restrict__ C,
                       int M, int N, int K) {
    __shared__ float As[16][65];
    __shared__ float Bs[16][65];
    const int tid = threadIdx.x;
    const int tx = tid & 15, ty = tid >> 4;
    const int m0 = blockIdx.y * 64, n0 = blockIdx.x * 64;
    float acc[4][4] = {};
    for (int k0 = 0; k0 < K; k0 += 16) {
#pragma unroll
        for (int r = 0; r < 4; ++r) {
            int flat = tid + 256 * r;
            int am = flat >> 4, ak = flat & 15;
            As[ak][am] = A[(size_t)(m0 + am) * K + k0 + ak];
            int bk = flat >> 6, bn = flat & 63;
            Bs[bk][bn] = W[(size_t)(k0 + bk) * N + n0 + bn];
        }
        __syncthreads();
#pragma unroll
        for (int kk = 0; kk < 16; ++kk) {
            float a[4], b[4];
#pragma unroll
            for (int i = 0; i < 4; ++i) a[i] = As[kk][ty * 4 + i];
#pragma unroll
            for (int j = 0; j < 4; ++j) b[j] = Bs[kk][tx * 4 + j];
#pragma unroll
            for (int i = 0; i < 4; ++i)
#pragma unroll
                for (int j = 0; j < 4; ++j) acc[i][j] += a[i] * b[j];
        }
        __syncthreads();
    }
#pragma unroll
    for (int i = 0; i < 4; ++i)
#pragma unroll
        for (int j = 0; j < 4; ++j) {
            int m = m0 + ty * 4 + i, n = n0 + tx * 4 + j;
            C[(size_t)m * N + n] = acc[i][j] + (bias ? bias[n] : 0.0f);
        }
}

// ---------------- W[K][N] fp32 -> Wt[N][K] bf16 hi (+lo) ----------------
__global__ void trans_split(const float* __restrict__ W, short* __restrict__ Whi,
                            short* __restrict__ Wlo, int K, int N) {
    __shared__ float tl[32][33];
    const int k0 = blockIdx.y * 32, n0 = blockIdx.x * 32;
    const int c = threadIdx.x & 31, r8 = threadIdx.x >> 5;
#pragma unroll
    for (int it = 0; it < 4; ++it) {
        int r = r8 + it * 8;
        tl[r][c] = W[(size_t)(k0 + r) * N + n0 + c];
    }
    __syncthreads();
#pragma unroll
    for (int it = 0; it < 4; ++it) {
        int r = r8 + it * 8;
        float x = tl[c][r];                      // = W[k0+c][n0+r]
        short hi = f2bf(x);
        Whi[(size_t)(n0 + r) * K + k0 + c] = hi;
        if (Wlo) Wlo[(size_t)(n0 + r) * K + k0 + c] = f2bf(x - bf2f(hi));
    }
}

// ---------------- MFMA GEMM: C[M,N] = A[M,K] @ B + bias ----------------
// B transposed bf16 [N][K]. AMODE: 0 = A bf16; 1 = A fp32 split bf16x3;
// 2 = A fp32 rounded to bf16 (single). VOUT: epilogue writes vtb bf16
// [kv][c][d][j] (V-projection fused with the chunk-transpose).
template <int AMODE, bool VOUT>
__global__ __launch_bounds__(256) void gemm_mfma(
        const void* __restrict__ Av, const short* __restrict__ Bhi,
        const short* __restrict__ Blo, const float* __restrict__ bias,
        float* __restrict__ C, short* __restrict__ vout, int M, int N, int K) {
    __shared__ short Ahs[128][40];
    __shared__ short Bhs[128][40];
    __shared__ short Als[AMODE == 1 ? 128 : 1][40];
    __shared__ short Bls[AMODE == 1 ? 128 : 1][40];
    const int tid = threadIdx.x;
    const int w = tid >> 6, lane = tid & 63, nl = lane & 15, quad = lane >> 4;
    const int wm = w >> 1, wn = w & 1;
    const int m0 = blockIdx.y * 128, n0 = blockIdx.x * 128;
    const int srow = tid >> 1, sseg = tid & 1;
    f32x4 acc[4][4];
#pragma unroll
    for (int i = 0; i < 4; ++i)
#pragma unroll
        for (int j = 0; j < 4; ++j) acc[i][j] = (f32x4){0.f, 0.f, 0.f, 0.f};

    for (int k0 = 0; k0 < K; k0 += 32) {
        if (AMODE != 0) {
            const float* A = (const float*)Av;
            const float* ap = A + (size_t)(m0 + srow) * K + k0 + sseg * 16;
            short8 hi0, hi1, lo0, lo1;
#pragma unroll
            for (int i = 0; i < 8; ++i) {
                float x = ap[i];
                short h = f2bf(x);
                hi0[i] = h; if (AMODE == 1) lo0[i] = f2bf(x - bf2f(h));
            }
#pragma unroll
            for (int i = 0; i < 8; ++i) {
                float x = ap[8 + i];
                short h = f2bf(x);
                hi1[i] = h; if (AMODE == 1) lo1[i] = f2bf(x - bf2f(h));
            }
            *(short8*)&Ahs[srow][sseg * 16] = hi0;
            *(short8*)&Ahs[srow][sseg * 16 + 8] = hi1;
            if (AMODE == 1) {
                *(short8*)&Als[srow][sseg * 16] = lo0;
                *(short8*)&Als[srow][sseg * 16 + 8] = lo1;
            }
        } else {
            const short* A = (const short*)Av;
            const short* ap = A + (size_t)(m0 + srow) * K + k0 + sseg * 16;
            *(short8*)&Ahs[srow][sseg * 16]     = *(const short8*)(ap);
            *(short8*)&Ahs[srow][sseg * 16 + 8] = *(const short8*)(ap + 8);
        }
        {
            const short* bh = Bhi + (size_t)(n0 + srow) * K + k0 + sseg * 16;
            *(short8*)&Bhs[srow][sseg * 16]     = *(const short8*)(bh);
            *(short8*)&Bhs[srow][sseg * 16 + 8] = *(const short8*)(bh + 8);
        }
        if (AMODE == 1) {
            const short* bl = Blo + (size_t)(n0 + srow) * K + k0 + sseg * 16;
            *(short8*)&Bls[srow][sseg * 16]     = *(const short8*)(bl);
            *(short8*)&Bls[srow][sseg * 16 + 8] = *(const short8*)(bl + 8);
        }
        __syncthreads();
        short8 af[4], bf_[4], al[4], bl_[4];
#pragma unroll
        for (int tm = 0; tm < 4; ++tm)
            af[tm] = *(const short8*)&Ahs[wm * 64 + tm * 16 + nl][quad * 8];
#pragma unroll
        for (int tn = 0; tn < 4; ++tn)
            bf_[tn] = *(const short8*)&Bhs[wn * 64 + tn * 16 + nl][quad * 8];
        if (AMODE == 1) {
#pragma unroll
            for (int tm = 0; tm < 4; ++tm)
                al[tm] = *(const short8*)&Als[wm * 64 + tm * 16 + nl][quad * 8];
#pragma unroll
            for (int tn = 0; tn < 4; ++tn)
                bl_[tn] = *(const short8*)&Bls[wn * 64 + tn * 16 + nl][quad * 8];
        }
#pragma unroll
        for (int tm = 0; tm < 4; ++tm)
#pragma unroll
            for (int tn = 0; tn < 4; ++tn) {
                acc[tm][tn] = __builtin_amdgcn_mfma_f32_16x16x32_bf16(af[tm], bf_[tn], acc[tm][tn], 0, 0, 0);
                if (AMODE == 1) {
                    acc[tm][tn] = __builtin_amdgcn_mfma_f32_16x16x32_bf16(af[tm], bl_[tn], acc[tm][tn], 0, 0, 0);
                    acc[tm][tn] = __builtin_amdgcn_mfma_f32_16x16x32_bf16(al[tm], bf_[tn], acc[tm][tn], 0, 0, 0);
                }
            }
        __syncthreads();
    }
#pragma unroll
    for (int tm = 0; tm < 4; ++tm)
#pragma unroll
        for (int tn = 0; tn < 4; ++tn)
#pragma unroll
            for (int r = 0; r < 4; ++r) {
                int m = m0 + wm * 64 + tm * 16 + quad * 4 + r;
                int n = n0 + wn * 64 + tn * 16 + nl;
                float v = acc[tm][tn][r] + (bias ? bias[n] : 0.0f);
                if (VOUT) {
                    int kv = n >> 7, d = n & 127, cc = m >> 7, j = m & 127;
                    vout[(((size_t)kv * Ncn + cc) * 128 + d) * 128 + j] = f2bf(v);
                } else {
                    C[(size_t)m * N + n] = v;
                }
            }
}

// ---------------- RoPE in-place on q and k; k also -> bf16 ----------------
__global__ void rope_kernel(float* __restrict__ q, float* __restrict__ k,
                            const float* __restrict__ cosb, const float* __restrict__ sinb,
                            short* __restrict__ kb) {
    int idx = blockIdx.x * blockDim.x + threadIdx.x;   // S*18*64
    int s = idx / (18 * 64);
    int r = idx % (18 * 64);
    int head = r >> 6;
    int d = r & 63;
    float c0 = cosb[s * 128 + d], c1 = cosb[s * 128 + d + 64];
    float s0 = sinb[s * 128 + d], s1 = sinb[s * 128 + d + 64];
    if (head < 16) {
        float* base = q + (size_t)s * 2048 + head * 128;
        float x0 = base[d], x1 = base[d + 64];
        base[d]      = x0 * c0 - x1 * s0;
        base[d + 64] = x1 * c1 + x0 * s1;
    } else {
        int kv = head - 16;
        float* base = k + (size_t)s * 256 + kv * 128;
        float x0 = base[d], x1 = base[d + 64];
        float y0 = x0 * c0 - x1 * s0;
        float y1 = x1 * c1 + x0 * s1;
        base[d] = y0; base[d + 64] = y1;
        short* ko = kb + ((size_t)kv * Sn + s) * 128;
        ko[d] = f2bf(y0); ko[d + 64] = f2bf(y1);
    }
}

// ---------------- V -> bf16, transposed per chunk (fallback path only) ----------
__global__ void conv_v(const float* __restrict__ v, short* __restrict__ vtb) {
    int idx = blockIdx.x * blockDim.x + threadIdx.x;   // S*256
    int pos = idx >> 8;
    int rem = idx & 255;
    int kv = rem >> 7, d = rem & 127;
    float val = v[(size_t)pos * 256 + kv * 128 + d];
    int c = pos >> 7, j = pos & 127;
    vtb[(((size_t)kv * Ncn + c) * 128 + d) * 128 + j] = f2bf(val);
}

// ---------------- per-chunk K stats (+ zero the tie-flag counter) ----------------
__global__ void chunk_stats(const float* __restrict__ k, float* __restrict__ kcm,
                            float* __restrict__ kcx, int* __restrict__ flags) {
    if (blockIdx.x == 0 && threadIdx.x == 0) flags[0] = 0;
    int c = blockIdx.x & 15, kv = blockIdx.x >> 4;
    int d = threadIdx.x;
    float sum = 0.f, mx = -INFINITY;
    for (int j = 0; j < 128; ++j) {
        float v = k[(size_t)(c * 128 + j) * 256 + kv * 128 + d];
        sum += v; mx = fmaxf(mx, v);
    }
    kcm[(kv * 16 + c) * 128 + d] = sum * (1.0f / 128.0f);
    kcx[(kv * 16 + c) * 128 + d] = mx;
}

// ---------------- block scores + top-8 -> chunk mask; flag genuine near-ties ----
__global__ void block_scores(const float* __restrict__ q, const float* __restrict__ kcm,
                             const float* __restrict__ kcx, unsigned int* __restrict__ mask32,
                             int* __restrict__ flags) {
    int qpos = blockIdx.x, kv = blockIdx.y;
    int t = threadIdx.x;          // 128: t = c*8 + g
    int c = t >> 3, g = t & 7;
    int h = kv * 8 + g;
    const float* qr = q + (size_t)qpos * 2048 + h * 128;
    const float* km = kcm + (kv * 16 + c) * 128;
    const float* kx = kcx + (kv * 16 + c) * 128;
    float dm = 0.f, dx = 0.f;
#pragma unroll 4
    for (int d = 0; d < 128; ++d) { float qv = qr[d]; dm += qv * km[d]; dx += qv * kx[d]; }
    float sg = (MIXLf * dm + (1.0f - MIXLf) * dx) * SCALEf;
    __shared__ float sh[16][8];
    __shared__ float vals[16];
    sh[c][g] = sg;
    __syncthreads();
    if (t < 16) {
        float mean = 0.f, mxv = -INFINITY;
#pragma unroll
        for (int gg = 0; gg < 8; ++gg) { mean += sh[t][gg]; mxv = fmaxf(mxv, sh[t][gg]); }
        mean *= 0.125f;
        float v = ALPHAf * mean + (1.0f - ALPHAf) * mxv;
        if (t * 128 > qpos) v = NEGf;
        vals[t] = v;
    }
    __syncthreads();
    if (t == 0) {
        unsigned int bits = 0;
        bool taken[16] = {};
        float v8 = -INFINITY;
        for (int it = 0; it < NBLK; ++it) {
            int best = 0; float bv = -INFINITY;
            for (int cc = 0; cc < 16; ++cc)
                if (!taken[cc] && vals[cc] > bv) { bv = vals[cc]; best = cc; }
            taken[best] = true;
            bits |= (1u << best);
            v8 = bv;
        }
        float v9 = -INFINITY;
        for (int cc = 0; cc < 16; ++cc)
            if (!taken[cc] && vals[cc] > v9) v9 = vals[cc];
        int lastc = qpos >> 7;
        unsigned int causal_bits = (1u << (lastc + 1)) - 1u;
        mask32[kv * 2048 + qpos] = bits & causal_bits;
        if (v9 > -0.5e9f && v8 - v9 < EPSGAP) {
            int idx = atomicAdd(flags, 1);
            if (idx < FLAGCAP) flags[1 + idx] = (kv << 16) | qpos;
        }
    }
}

// ---------------- exact fp32 q for flagged rows (parallel) ----------------
__global__ __launch_bounds__(256) void fixup_q(
        const float* __restrict__ hs, const float* __restrict__ Wq,
        const float* __restrict__ bq, const float* __restrict__ cosb,
        const float* __restrict__ sinb, const int* __restrict__ flags,
        float* __restrict__ qfix) {
    int cnt = flags[0]; if (cnt > FLAGCAP) cnt = FLAGCAP;
    const int items = cnt * 8;
    const int tid = threadIdx.x;
    __shared__ float hssh[2048];
    __shared__ float part[2][128];
    __shared__ float qrow[128];
    for (int item = blockIdx.x; item < items; item += gridDim.x) {
        int i = item >> 3, g = item & 7;
        int e = flags[1 + i];
        int kv = e >> 16, qpos = e & 0xffff;
        for (int j = tid; j < 2048; j += 256) hssh[j] = hs[(size_t)qpos * 2048 + j];
        __syncthreads();
        int d = tid & 127, half = tid >> 7;
        int col = (kv * 8 + g) * 128 + d;
        float s0 = 0.f, s1 = 0.f, s2 = 0.f, s3 = 0.f;
        const float* wp = Wq + (size_t)(half * 1024) * 2048 + col;
        const float* hp = hssh + half * 1024;
        for (int k = 0; k < 1024; k += 4) {
            s0 += hp[k + 0] * wp[(size_t)(k + 0) * 2048];
            s1 += hp[k + 1] * wp[(size_t)(k + 1) * 2048];
            s2 += hp[k + 2] * wp[(size_t)(k + 2) * 2048];
            s3 += hp[k + 3] * wp[(size_t)(k + 3) * 2048];
        }
        part[half][d] = (s0 + s1) + (s2 + s3);
        __syncthreads();
        if (tid < 128) qrow[tid] = part[0][tid] + part[1][tid] + bq[col];
        __syncthreads();
        if (tid < 64) {
            int dd = tid;
            float c0 = cosb[qpos * 128 + dd], c1 = cosb[qpos * 128 + dd + 64];
            float s0_ = sinb[qpos * 128 + dd], s1_ = sinb[qpos * 128 + dd + 64];
            float x0 = qrow[dd], x1 = qrow[dd + 64];
            qfix[(size_t)i * 1024 + g * 128 + dd]      = x0 * c0 - x1 * s0_;
            qfix[(size_t)i * 1024 + g * 128 + dd + 64] = x1 * c1 + x0 * s1_;
        }
        __syncthreads();
    }
}

// ---------------- redo top-8 for flagged rows from exact q ----------------
__global__ void fixup_sel(const float* __restrict__ qfix, const float* __restrict__ kcm,
                          const float* __restrict__ kcx, const int* __restrict__ flags,
                          unsigned int* __restrict__ mask32) {
    int cnt = flags[0]; if (cnt > FLAGCAP) cnt = FLAGCAP;
    int i = blockIdx.x;
    if (i >= cnt) return;
    int e = flags[1 + i];
    int kv = e >> 16, qpos = e & 0xffff;
    int t = threadIdx.x;
    int c = t >> 3, g = t & 7;
    const float* qr = qfix + (size_t)i * 1024 + g * 128;
    const float* km = kcm + (kv * 16 + c) * 128;
    const float* kx = kcx + (kv * 16 + c) * 128;
    float dm = 0.f, dx = 0.f;
#pragma unroll 4
    for (int d = 0; d < 128; ++d) { float qv = qr[d]; dm += qv * km[d]; dx += qv * kx[d]; }
    float sg = (MIXLf * dm + (1.0f - MIXLf) * dx) * SCALEf;
    __shared__ float sh[16][8];
    __shared__ float vals[16];
    sh[c][g] = sg;
    __syncthreads();
    if (t < 16) {
        float mean = 0.f, mxv = -INFINITY;
#pragma unroll
        for (int gg = 0; gg < 8; ++gg) { mean += sh[t][gg]; mxv = fmaxf(mxv, sh[t][gg]); }
        mean *= 0.125f;
        float v = ALPHAf * mean + (1.0f - ALPHAf) * mxv;
        if (t * 128 > qpos) v = NEGf;
        vals[t] = v;
    }
    __syncthreads();
    if (t == 0) {
        unsigned int bits = 0;
        bool taken[16] = {};
        for (int it = 0; it < NBLK; ++it) {
            int best = 0; float bv = -INFINITY;
            for (int cc = 0; cc < 16; ++cc)
                if (!taken[cc] && vals[cc] > bv) { bv = vals[cc]; best = cc; }
            taken[best] = true;
            bits |= (1u << best);
        }
        int lastc = qpos >> 7;
        unsigned int causal_bits = (1u << (lastc + 1)) - 1u;
        mask32[kv * 2048 + qpos] = bits & causal_bits;
    }
}

// ---------------- MFMA flash attention (LDS-staged K/V) ----------------
// Block = 64-row tile x head; 4 waves = 4 independent 16-row strips (R7 math).
// Chunk loop over the block-uniform UNION of strip chunk-lists; K & V chunks
// staged into padded LDS cooperatively (coalesced, all loads in flight, one
// drain) -> fragments via ds_read_b128. P reuses the K region post-QK.
__global__ __launch_bounds__(256, 4) void attn_mfma(
        float* __restrict__ qbuf, const short* __restrict__ kb,
        const short* __restrict__ vtb, const unsigned int* __restrict__ mask32,
        const int* __restrict__ am, short* __restrict__ ab) {
    __shared__ short Kl[128 * KROW];   // 33,280 B; rows [w*16..w*16+16) reused as P
    __shared__ short Vl[128 * KROW];   // 33,280 B
    __shared__ unsigned ub[4];
    const int tid = threadIdx.x;
    const int w = tid >> 6, lane = tid & 63;
    const int nl = lane & 15, quad = lane >> 4;
    const int h = blockIdx.y, kv = h >> 3;
    const int r0 = (blockIdx.x * 4 + w) * 16;   // this wave's strip

    int qpos[4];
    unsigned rb[4];
#pragma unroll
    for (int r = 0; r < 4; ++r) {
        qpos[r] = r0 + quad * 4 + r;
        rb[r] = mask32[kv * Sn + qpos[r]];
    }
    unsigned bits = mask32[kv * Sn + r0 + nl];
#pragma unroll
    for (int off = 1; off < 64; off <<= 1) bits |= __shfl_xor(bits, off, 64);
    int wl = (r0 >= 15) ? ((r0 - 15) >> 7) : 0;
    int wh = (r0 + 15) >> 7;
    for (int c = wl; c <= wh; ++c) bits |= (1u << c);
    const int cmw = (r0 + 15) >> 7;
    bits &= (1u << (cmw + 1)) - 1u;
    if (lane == 0) ub[w] = bits;

    short8 qf[4];
    const float* qrow = qbuf + (size_t)(r0 + nl) * 2048 + h * 128;
#pragma unroll
    for (int ks = 0; ks < 4; ++ks) {
        float4 a = *(const float4*)(qrow + ks * 32 + quad * 8);
        float4 b = *(const float4*)(qrow + ks * 32 + quad * 8 + 4);
        short8 v;
        v[0] = f2bf(a.x); v[1] = f2bf(a.y); v[2] = f2bf(a.z); v[3] = f2bf(a.w);
        v[4] = f2bf(b.x); v[5] = f2bf(b.y); v[6] = f2bf(b.z); v[7] = f2bf(b.w);
        qf[ks] = v;
    }

    f32x4 oacc[8];
#pragma unroll
    for (int dt = 0; dt < 8; ++dt) oacc[dt] = (f32x4){0.f, 0.f, 0.f, 0.f};
    float m[4] = {-INFINITY, -INFINITY, -INFINITY, -INFINITY};
    float l[4] = {0.f, 0.f, 0.f, 0.f};

    __syncthreads();
    const unsigned un = ub[0] | ub[1] | ub[2] | ub[3];   // block-uniform
    const short* kcb0 = kb + (size_t)kv * Sn * 128;
    const short* vcb0 = vtb + (size_t)kv * Ncn * 128 * 128;
    short* Pb = &Kl[(w * 16) * KROW];                    // this wave's P strip

    unsigned remb = un;
    while (remb) {
        const int c = __builtin_ctz(remb);
        remb &= remb - 1;
        __syncthreads();                 // prior chunk's P/V reads complete
        // ---- cooperative staging: 16 independent 16B loads/thread, 1 drain ----
        const short* ksrc = kcb0 + (size_t)c * 128 * 128;
        const short* vsrc = vcb0 + (size_t)c * 128 * 128;
        short8 kst[8], vst[8];
#pragma unroll
        for (int i = 0; i < 8; ++i) {
            int e = i * 256 + tid;
            kst[i] = *(const short8*)(ksrc + e * 8);
            vst[i] = *(const short8*)(vsrc + e * 8);
        }
#pragma unroll
        for (int i = 0; i < 8; ++i) {
            int e = i * 256 + tid;
            int row = e >> 4, col = (e & 15) * 8;
            *(short8*)&Kl[row * KROW + col] = kst[i];
            *(short8*)&Vl[row * KROW + col] = vst[i];
        }
        __syncthreads();                 // chunk staged
        const bool mine = (bits >> c) & 1u;
        f32x4 sacc[8];
        if (mine) {
#pragma unroll
            for (int t = 0; t < 8; ++t) {
                const short* krow = &Kl[(t * 16 + nl) * KROW];
                f32x4 a = (f32x4){0.f, 0.f, 0.f, 0.f};
#pragma unroll
                for (int ks = 0; ks < 4; ++ks) {
                    short8 kf = *(const short8*)(krow + ks * 32 + quad * 8);
                    a = __builtin_amdgcn_mfma_f32_16x16x32_bf16(qf[ks], kf, a, 0, 0, 0);
                }
                sacc[t] = a;
            }
        }
        __syncthreads();                 // K reads done (P may overwrite Kl)
        if (mine) {
            float cmax[4] = {-INFINITY, -INFINITY, -INFINITY, -INFINITY};
#pragma unroll
            for (int t = 0; t < 8; ++t) {
                int kp = c * 128 + t * 16 + nl;
                bool amok = am[kp] != 0;
#pragma unroll
                for (int r = 0; r < 4; ++r) {
                    float s = sacc[t][r] * SCALEf;
                    bool ok = (kp <= qpos[r]) && amok &&
                              (((rb[r] >> c) & 1u) || (qpos[r] - kp) < WINn);
                    s = ok ? s : NEGf;
                    sacc[t][r] = s;
                    cmax[r] = fmaxf(cmax[r], s);
                }
            }
#pragma unroll
            for (int r = 0; r < 4; ++r)
#pragma unroll
                for (int off = 1; off < 16; off <<= 1)
                    cmax[r] = fmaxf(cmax[r], __shfl_xor(cmax[r], off, 64));
            float fac[4], rsum[4];
#pragma unroll
            for (int r = 0; r < 4; ++r) {
                float newm = fmaxf(m[r], cmax[r]);
                fac[r] = __expf(m[r] - newm);
                m[r] = newm;
                rsum[r] = 0.f;
            }
#pragma unroll
            for (int t = 0; t < 8; ++t)
#pragma unroll
                for (int r = 0; r < 4; ++r) {
                    float p = __expf(sacc[t][r] - m[r]);
                    rsum[r] += p;
                    Pb[(quad * 4 + r) * KROW + t * 16 + nl] = f2bf(p);
                }
#pragma unroll
            for (int r = 0; r < 4; ++r) {
#pragma unroll
                for (int off = 1; off < 16; off <<= 1)
                    rsum[r] += __shfl_xor(rsum[r], off, 64);
                l[r] = l[r] * fac[r] + rsum[r];
            }
#pragma unroll
            for (int dt = 0; dt < 8; ++dt)
#pragma unroll
                for (int r = 0; r < 4; ++r) oacc[dt][r] *= fac[r];
            short8 pf[4];
            const short* prow = &Pb[nl * KROW];
#pragma unroll
            for (int ks = 0; ks < 4; ++ks) pf[ks] = *(const short8*)(prow + ks * 32 + quad * 8);
#pragma unroll
            for (int dt = 0; dt < 8; ++dt) {
                const short* vrow = &Vl[(dt * 16 + nl) * KROW];
#pragma unroll
                for (int ks = 0; ks < 4; ++ks) {
                    short8 vf = *(const short8*)(vrow + ks * 32 + quad * 8);
                    oacc[dt] = __builtin_amdgcn_mfma_f32_16x16x32_bf16(pf[ks], vf, oacc[dt], 0, 0, 0);
                }
            }
        }
    }
    float inv[4];
#pragma unroll
    for (int r = 0; r < 4; ++r) inv[r] = 1.0f / l[r];
#pragma unroll
    for (int dt = 0; dt < 8; ++dt)
#pragma unroll
        for (int r = 0; r < 4; ++r) {
            float val = oacc[dt][r] * inv[r];
            size_t off = (size_t)qpos[r] * 2048 + h * 128 + dt * 16 + nl;
            qbuf[off] = val;
            ab[off] = f2bf(val);
        }
}

extern "C" void kernel_launch(void* const* d_in, const int* in_sizes, int n_in,
                              void* d_out, int out_size, void* d_ws, size_t ws_size,
                              hipStream_t stream) {
    const float* hs   = (const float*)d_in[0];
    const float* cosb = (const float*)d_in[1];
    const float* sinb = (const float*)d_in[2];
    const int*   am   = (const int*)d_in[3];
    const float* Wq = (const float*)d_in[5];
    const float* bq = (const float*)d_in[6];
    const float* Wk = (const float*)d_in[7];
    const float* bk = (const float*)d_in[8];
    const float* Wv = (const float*)d_in[9];
    const float* bv = (const float*)d_in[10];
    const float* Wo = (const float*)d_in[11];
    float* out = (float*)d_out;

    float* qbuf = (float*)d_ws;                       // 4,194,304 f
    float* kbuf = qbuf + (size_t)Sn * HIDn;           // 524,288 f
    float* vbuf = kbuf + (size_t)Sn * HKVn * HDn;     // 524,288 f (fallback V / big-path WvT)
    float* kcm  = vbuf + (size_t)Sn * HKVn * HDn;     // 4096 f
    float* kcx  = kcm + 4096;                         // 4096 f
    unsigned int* mask32 = (unsigned int*)(kcx + 4096);  // 4096 u32
    int* flags = (int*)(mask32 + 4096);               // 4096 i32
    short* kb  = (short*)(flags + 4096);              // 524,288 s
    short* vtb = kb + (size_t)HKVn * Sn * HDn;        // 524,288 s
    char* P = (char*)(vtb + (size_t)HKVn * Sn * HDn);
    const size_t WSZ = (size_t)HIDn * HIDn * sizeof(short);   // 8,388,608 B
    size_t base = (size_t)((char*)P - (char*)d_ws);
    bool big = ws_size >= base + 2 * WSZ;

    dim3 blk(256);
    if (big) {
        short* W1 = (short*)P;              // Wq hi^T; later qfix; later Wo^T
        short* W2 = (short*)(P + WSZ);      // Wq lo^T; later ab
        short* ab = W2;
        float* qfix = (float*)W1;
        short* WvT = (short*)vbuf;          // 256*2048 s = 1 MB (vbuf unused on big path)
        trans_split<<<dim3(64, 64), blk, 0, stream>>>(Wq, W1, W2, HIDn, HIDn);
        gemm_mfma<1, false><<<dim3(16, 16), blk, 0, stream>>>(hs, W1, W2, bq, qbuf, nullptr, Sn, HIDn, HIDn);
        gemm64<<<dim3((HKVn * HDn) / 64, Sn / 64), blk, 0, stream>>>(hs, Wk, bk, kbuf, Sn, HKVn * HDn, HIDn);
        trans_split<<<dim3(8, 64), blk, 0, stream>>>(Wv, WvT, nullptr, HIDn, HKVn * HDn);
        gemm_mfma<2, true><<<dim3(2, 16), blk, 0, stream>>>(hs, WvT, nullptr, bv, nullptr, vtb, Sn, HKVn * HDn, HIDn);
        rope_kernel<<<(Sn * 18 * 64) / 256, blk, 0, stream>>>(qbuf, kbuf, cosb, sinb, kb);
        chunk_stats<<<HKVn * Ncn, 128, 0, stream>>>(kbuf, kcm, kcx, flags);
        block_scores<<<dim3(Sn, HKVn), 128, 0, stream>>>(qbuf, kcm, kcx, mask32, flags);
        fixup_q<<<2048, blk, 0, stream>>>(hs, Wq, bq, cosb, sinb, flags, qfix);
        fixup_sel<<<FLAGCAP, 128, 0, stream>>>(qfix, kcm, kcx, flags, mask32);
        attn_mfma<<<dim3(Sn / 64, HQn), blk, 0, stream>>>(qbuf, kb, vtb, mask32, am, ab);
        trans_split<<<dim3(64, 64), blk, 0, stream>>>(Wo, W1, nullptr, HIDn, HIDn);
        gemm_mfma<0, false><<<dim3(16, 16), blk, 0, stream>>>(ab, W1, nullptr, nullptr, out, nullptr, Sn, HIDn, HIDn);
    } else {
        short* ab = (short*)P;
        gemm64<<<dim3(HIDn / 64, Sn / 64), blk, 0, stream>>>(hs, Wq, bq, qbuf, Sn, HIDn, HIDn);
        gemm64<<<dim3((HKVn * HDn) / 64, Sn / 64), blk, 0, stream>>>(hs, Wk, bk, kbuf, Sn, HKVn * HDn, HIDn);
        gemm64<<<dim3((HKVn * HDn) / 64, Sn / 64), blk, 0, stream>>>(hs, Wv, bv, vbuf, Sn, HKVn * HDn, HIDn);
        rope_kernel<<<(Sn * 18 * 64) / 256, blk, 0, stream>>>(qbuf, kbuf, cosb, sinb, kb);
        conv_v<<<(Sn * 256) / 256, blk, 0, stream>>>(vbuf, vtb);
        chunk_stats<<<HKVn * Ncn, 128, 0, stream>>>(kbuf, kcm, kcx, flags);
        block_scores<<<dim3(Sn, HKVn), 128, 0, stream>>>(qbuf, kcm, kcx, mask32, flags);
        attn_mfma<<<dim3(Sn / 64, HQn), blk, 0, stream>>>(qbuf, kb, vtb, mask32, am, ab);
        gemm64<<<dim3(HIDn / 64, Sn / 64), blk, 0, stream>>>(qbuf, Wo, nullptr, out, Sn, HIDn, HIDn);
    }
}

// Round 11
// 962.878 us; speedup vs baseline: 1.0884x; 1.0732x over previous
//
#include <hip/hip_runtime.h>
#include <hip/hip_bf16.h>

#define Sn    2048
#define HIDn  2048
#define HQn   16
#define HKVn  2
#define HDn   128
#define Gn    8
#define CSn   128
#define Ncn   16
#define NBLK  8
#define WINn  16
#define SCALEf 0.08838834764831845f   // 128^-0.5
#define NEGf  (-1.0e9f)
#define ALPHAf 0.8f
#define MIXLf  0.5f
#define EPSGAP 2.0e-3f
#define FLAGCAP 2040

typedef __attribute__((ext_vector_type(8))) short short8;   // 8 bf16 = 4 VGPRs
typedef __attribute__((ext_vector_type(4))) float f32x4;

static __device__ __forceinline__ short f2bf(float x) {
    union { float f; unsigned u; } v; v.f = x;
    unsigned r = v.u + 0x7fffu + ((v.u >> 16) & 1u);
    return (short)(r >> 16);
}
static __device__ __forceinline__ float bf2f(short b) {
    union { float f; unsigned u; } v; v.u = ((unsigned)(unsigned short)b) << 16;
    return v.f;
}

// ---------------- fp32 GEMM (K proj + fallback path) ----------------
__global__ void gemm64(const float* __restrict__ A, const float* __restrict__ W,
                       const float* __restrict__ bias, float* __restrict__ C,
                       int M, int N, int K) {
    __shared__ float As[16][65];
    __shared__ float Bs[16][65];
    const int tid = threadIdx.x;
    const int tx = tid & 15, ty = tid >> 4;
    const int m0 = blockIdx.y * 64, n0 = blockIdx.x * 64;
    float acc[4][4] = {};
    for (int k0 = 0; k0 < K; k0 += 16) {
#pragma unroll
        for (int r = 0; r < 4; ++r) {
            int flat = tid + 256 * r;
            int am = flat >> 4, ak = flat & 15;
            As[ak][am] = A[(size_t)(m0 + am) * K + k0 + ak];
            int bk = flat >> 6, bn = flat & 63;
            Bs[bk][bn] = W[(size_t)(k0 + bk) * N + n0 + bn];
        }
        __syncthreads();
#pragma unroll
        for (int kk = 0; kk < 16; ++kk) {
            float a[4], b[4];
#pragma unroll
            for (int i = 0; i < 4; ++i) a[i] = As[kk][ty * 4 + i];
#pragma unroll
            for (int j = 0; j < 4; ++j) b[j] = Bs[kk][tx * 4 + j];
#pragma unroll
            for (int i = 0; i < 4; ++i)
#pragma unroll
                for (int j = 0; j < 4; ++j) acc[i][j] += a[i] * b[j];
        }
        __syncthreads();
    }
#pragma unroll
    for (int i = 0; i < 4; ++i)
#pragma unroll
        for (int j = 0; j < 4; ++j) {
            int m = m0 + ty * 4 + i, n = n0 + tx * 4 + j;
            C[(size_t)m * N + n] = acc[i][j] + (bias ? bias[n] : 0.0f);
        }
}

// ---------------- W[K][N] fp32 -> Wt[N][K] bf16 hi (+lo) ----------------
__global__ void trans_split(const float* __restrict__ W, short* __restrict__ Whi,
                            short* __restrict__ Wlo, int K, int N) {
    __shared__ float tl[32][33];
    const int k0 = blockIdx.y * 32, n0 = blockIdx.x * 32;
    const int c = threadIdx.x & 31, r8 = threadIdx.x >> 5;
#pragma unroll
    for (int it = 0; it < 4; ++it) {
        int r = r8 + it * 8;
        tl[r][c] = W[(size_t)(k0 + r) * N + n0 + c];
    }
    __syncthreads();
#pragma unroll
    for (int it = 0; it < 4; ++it) {
        int r = r8 + it * 8;
        float x = tl[c][r];                      // = W[k0+c][n0+r]
        short hi = f2bf(x);
        Whi[(size_t)(n0 + r) * K + k0 + c] = hi;
        if (Wlo) Wlo[(size_t)(n0 + r) * K + k0 + c] = f2bf(x - bf2f(hi));
    }
}

// ---------------- MFMA GEMM: C[M,N] = A[M,K] @ B + bias ----------------
// B transposed bf16 [N][K]. AMODE: 0 = A bf16; 1 = A fp32 split bf16x3;
// 2 = A fp32 rounded to bf16 (single). VOUT: epilogue writes vtb bf16
// [kv][c][d][j] (V-projection fused with the chunk-transpose).
template <int AMODE, bool VOUT>
__global__ __launch_bounds__(256) void gemm_mfma(
        const void* __restrict__ Av, const short* __restrict__ Bhi,
        const short* __restrict__ Blo, const float* __restrict__ bias,
        float* __restrict__ C, short* __restrict__ vout, int M, int N, int K) {
    __shared__ short Ahs[128][40];
    __shared__ short Bhs[128][40];
    __shared__ short Als[AMODE == 1 ? 128 : 1][40];
    __shared__ short Bls[AMODE == 1 ? 128 : 1][40];
    const int tid = threadIdx.x;
    const int w = tid >> 6, lane = tid & 63, nl = lane & 15, quad = lane >> 4;
    const int wm = w >> 1, wn = w & 1;
    const int m0 = blockIdx.y * 128, n0 = blockIdx.x * 128;
    const int srow = tid >> 1, sseg = tid & 1;
    f32x4 acc[4][4];
#pragma unroll
    for (int i = 0; i < 4; ++i)
#pragma unroll
        for (int j = 0; j < 4; ++j) acc[i][j] = (f32x4){0.f, 0.f, 0.f, 0.f};

    for (int k0 = 0; k0 < K; k0 += 32) {
        if (AMODE != 0) {
            const float* A = (const float*)Av;
            const float* ap = A + (size_t)(m0 + srow) * K + k0 + sseg * 16;
            short8 hi0, hi1, lo0, lo1;
#pragma unroll
            for (int i = 0; i < 8; ++i) {
                float x = ap[i];
                short h = f2bf(x);
                hi0[i] = h; if (AMODE == 1) lo0[i] = f2bf(x - bf2f(h));
            }
#pragma unroll
            for (int i = 0; i < 8; ++i) {
                float x = ap[8 + i];
                short h = f2bf(x);
                hi1[i] = h; if (AMODE == 1) lo1[i] = f2bf(x - bf2f(h));
            }
            *(short8*)&Ahs[srow][sseg * 16] = hi0;
            *(short8*)&Ahs[srow][sseg * 16 + 8] = hi1;
            if (AMODE == 1) {
                *(short8*)&Als[srow][sseg * 16] = lo0;
                *(short8*)&Als[srow][sseg * 16 + 8] = lo1;
            }
        } else {
            const short* A = (const short*)Av;
            const short* ap = A + (size_t)(m0 + srow) * K + k0 + sseg * 16;
            *(short8*)&Ahs[srow][sseg * 16]     = *(const short8*)(ap);
            *(short8*)&Ahs[srow][sseg * 16 + 8] = *(const short8*)(ap + 8);
        }
        {
            const short* bh = Bhi + (size_t)(n0 + srow) * K + k0 + sseg * 16;
            *(short8*)&Bhs[srow][sseg * 16]     = *(const short8*)(bh);
            *(short8*)&Bhs[srow][sseg * 16 + 8] = *(const short8*)(bh + 8);
        }
        if (AMODE == 1) {
            const short* bl = Blo + (size_t)(n0 + srow) * K + k0 + sseg * 16;
            *(short8*)&Bls[srow][sseg * 16]     = *(const short8*)(bl);
            *(short8*)&Bls[srow][sseg * 16 + 8] = *(const short8*)(bl + 8);
        }
        __syncthreads();
        short8 af[4], bf_[4], al[4], bl_[4];
#pragma unroll
        for (int tm = 0; tm < 4; ++tm)
            af[tm] = *(const short8*)&Ahs[wm * 64 + tm * 16 + nl][quad * 8];
#pragma unroll
        for (int tn = 0; tn < 4; ++tn)
            bf_[tn] = *(const short8*)&Bhs[wn * 64 + tn * 16 + nl][quad * 8];
        if (AMODE == 1) {
#pragma unroll
            for (int tm = 0; tm < 4; ++tm)
                al[tm] = *(const short8*)&Als[wm * 64 + tm * 16 + nl][quad * 8];
#pragma unroll
            for (int tn = 0; tn < 4; ++tn)
                bl_[tn] = *(const short8*)&Bls[wn * 64 + tn * 16 + nl][quad * 8];
        }
#pragma unroll
        for (int tm = 0; tm < 4; ++tm)
#pragma unroll
            for (int tn = 0; tn < 4; ++tn) {
                acc[tm][tn] = __builtin_amdgcn_mfma_f32_16x16x32_bf16(af[tm], bf_[tn], acc[tm][tn], 0, 0, 0);
                if (AMODE == 1) {
                    acc[tm][tn] = __builtin_amdgcn_mfma_f32_16x16x32_bf16(af[tm], bl_[tn], acc[tm][tn], 0, 0, 0);
                    acc[tm][tn] = __builtin_amdgcn_mfma_f32_16x16x32_bf16(al[tm], bf_[tn], acc[tm][tn], 0, 0, 0);
                }
            }
        __syncthreads();
    }
#pragma unroll
    for (int tm = 0; tm < 4; ++tm)
#pragma unroll
        for (int tn = 0; tn < 4; ++tn)
#pragma unroll
            for (int r = 0; r < 4; ++r) {
                int m = m0 + wm * 64 + tm * 16 + quad * 4 + r;
                int n = n0 + wn * 64 + tn * 16 + nl;
                float v = acc[tm][tn][r] + (bias ? bias[n] : 0.0f);
                if (VOUT) {
                    int kv = n >> 7, d = n & 127, cc = m >> 7, j = m & 127;
                    vout[(((size_t)kv * Ncn + cc) * 128 + d) * 128 + j] = f2bf(v);
                } else {
                    C[(size_t)m * N + n] = v;
                }
            }
}

// ---------------- RoPE in-place on q and k; k also -> bf16 ----------------
__global__ void rope_kernel(float* __restrict__ q, float* __restrict__ k,
                            const float* __restrict__ cosb, const float* __restrict__ sinb,
                            short* __restrict__ kb) {
    int idx = blockIdx.x * blockDim.x + threadIdx.x;   // S*18*64
    int s = idx / (18 * 64);
    int r = idx % (18 * 64);
    int head = r >> 6;
    int d = r & 63;
    float c0 = cosb[s * 128 + d], c1 = cosb[s * 128 + d + 64];
    float s0 = sinb[s * 128 + d], s1 = sinb[s * 128 + d + 64];
    if (head < 16) {
        float* base = q + (size_t)s * 2048 + head * 128;
        float x0 = base[d], x1 = base[d + 64];
        base[d]      = x0 * c0 - x1 * s0;
        base[d + 64] = x1 * c1 + x0 * s1;
    } else {
        int kv = head - 16;
        float* base = k + (size_t)s * 256 + kv * 128;
        float x0 = base[d], x1 = base[d + 64];
        float y0 = x0 * c0 - x1 * s0;
        float y1 = x1 * c1 + x0 * s1;
        base[d] = y0; base[d + 64] = y1;
        short* ko = kb + ((size_t)kv * Sn + s) * 128;
        ko[d] = f2bf(y0); ko[d + 64] = f2bf(y1);
    }
}

// ---------------- V -> bf16, transposed per chunk (fallback path only) ----------
__global__ void conv_v(const float* __restrict__ v, short* __restrict__ vtb) {
    int idx = blockIdx.x * blockDim.x + threadIdx.x;   // S*256
    int pos = idx >> 8;
    int rem = idx & 255;
    int kv = rem >> 7, d = rem & 127;
    float val = v[(size_t)pos * 256 + kv * 128 + d];
    int c = pos >> 7, j = pos & 127;
    vtb[(((size_t)kv * Ncn + c) * 128 + d) * 128 + j] = f2bf(val);
}

// ---------------- per-chunk K stats (+ zero the tie-flag counter) ----------------
__global__ void chunk_stats(const float* __restrict__ k, float* __restrict__ kcm,
                            float* __restrict__ kcx, int* __restrict__ flags) {
    if (blockIdx.x == 0 && threadIdx.x == 0) flags[0] = 0;
    int c = blockIdx.x & 15, kv = blockIdx.x >> 4;
    int d = threadIdx.x;
    float sum = 0.f, mx = -INFINITY;
    for (int j = 0; j < 128; ++j) {
        float v = k[(size_t)(c * 128 + j) * 256 + kv * 128 + d];
        sum += v; mx = fmaxf(mx, v);
    }
    kcm[(kv * 16 + c) * 128 + d] = sum * (1.0f / 128.0f);
    kcx[(kv * 16 + c) * 128 + d] = mx;
}

// ---------------- block scores + top-8 -> chunk mask; flag genuine near-ties ----
__global__ void block_scores(const float* __restrict__ q, const float* __restrict__ kcm,
                             const float* __restrict__ kcx, unsigned int* __restrict__ mask32,
                             int* __restrict__ flags) {
    int qpos = blockIdx.x, kv = blockIdx.y;
    int t = threadIdx.x;          // 128: t = c*8 + g
    int c = t >> 3, g = t & 7;
    int h = kv * 8 + g;
    const float* qr = q + (size_t)qpos * 2048 + h * 128;
    const float* km = kcm + (kv * 16 + c) * 128;
    const float* kx = kcx + (kv * 16 + c) * 128;
    float dm = 0.f, dx = 0.f;
#pragma unroll 4
    for (int d = 0; d < 128; ++d) { float qv = qr[d]; dm += qv * km[d]; dx += qv * kx[d]; }
    float sg = (MIXLf * dm + (1.0f - MIXLf) * dx) * SCALEf;
    __shared__ float sh[16][8];
    __shared__ float vals[16];
    sh[c][g] = sg;
    __syncthreads();
    if (t < 16) {
        float mean = 0.f, mxv = -INFINITY;
#pragma unroll
        for (int gg = 0; gg < 8; ++gg) { mean += sh[t][gg]; mxv = fmaxf(mxv, sh[t][gg]); }
        mean *= 0.125f;
        float v = ALPHAf * mean + (1.0f - ALPHAf) * mxv;
        if (t * 128 > qpos) v = NEGf;
        vals[t] = v;
    }
    __syncthreads();
    if (t == 0) {
        unsigned int bits = 0;
        bool taken[16] = {};
        float v8 = -INFINITY;
        for (int it = 0; it < NBLK; ++it) {
            int best = 0; float bv = -INFINITY;
            for (int cc = 0; cc < 16; ++cc)
                if (!taken[cc] && vals[cc] > bv) { bv = vals[cc]; best = cc; }
            taken[best] = true;
            bits |= (1u << best);
            v8 = bv;
        }
        float v9 = -INFINITY;
        for (int cc = 0; cc < 16; ++cc)
            if (!taken[cc] && vals[cc] > v9) v9 = vals[cc];
        int lastc = qpos >> 7;
        unsigned int causal_bits = (1u << (lastc + 1)) - 1u;
        mask32[kv * 2048 + qpos] = bits & causal_bits;
        if (v9 > -0.5e9f && v8 - v9 < EPSGAP) {
            int idx = atomicAdd(flags, 1);
            if (idx < FLAGCAP) flags[1 + idx] = (kv << 16) | qpos;
        }
    }
}

// ---------------- exact fp32 q for flagged rows (parallel) ----------------
__global__ __launch_bounds__(256) void fixup_q(
        const float* __restrict__ hs, const float* __restrict__ Wq,
        const float* __restrict__ bq, const float* __restrict__ cosb,
        const float* __restrict__ sinb, const int* __restrict__ flags,
        float* __restrict__ qfix) {
    int cnt = flags[0]; if (cnt > FLAGCAP) cnt = FLAGCAP;
    const int items = cnt * 8;
    const int tid = threadIdx.x;
    __shared__ float hssh[2048];
    __shared__ float part[2][128];
    __shared__ float qrow[128];
    for (int item = blockIdx.x; item < items; item += gridDim.x) {
        int i = item >> 3, g = item & 7;
        int e = flags[1 + i];
        int kv = e >> 16, qpos = e & 0xffff;
        for (int j = tid; j < 2048; j += 256) hssh[j] = hs[(size_t)qpos * 2048 + j];
        __syncthreads();
        int d = tid & 127, half = tid >> 7;
        int col = (kv * 8 + g) * 128 + d;
        float s0 = 0.f, s1 = 0.f, s2 = 0.f, s3 = 0.f;
        const float* wp = Wq + (size_t)(half * 1024) * 2048 + col;
        const float* hp = hssh + half * 1024;
        for (int k = 0; k < 1024; k += 4) {
            s0 += hp[k + 0] * wp[(size_t)(k + 0) * 2048];
            s1 += hp[k + 1] * wp[(size_t)(k + 1) * 2048];
            s2 += hp[k + 2] * wp[(size_t)(k + 2) * 2048];
            s3 += hp[k + 3] * wp[(size_t)(k + 3) * 2048];
        }
        part[half][d] = (s0 + s1) + (s2 + s3);
        __syncthreads();
        if (tid < 128) qrow[tid] = part[0][tid] + part[1][tid] + bq[col];
        __syncthreads();
        if (tid < 64) {
            int dd = tid;
            float c0 = cosb[qpos * 128 + dd], c1 = cosb[qpos * 128 + dd + 64];
            float s0_ = sinb[qpos * 128 + dd], s1_ = sinb[qpos * 128 + dd + 64];
            float x0 = qrow[dd], x1 = qrow[dd + 64];
            qfix[(size_t)i * 1024 + g * 128 + dd]      = x0 * c0 - x1 * s0_;
            qfix[(size_t)i * 1024 + g * 128 + dd + 64] = x1 * c1 + x0 * s1_;
        }
        __syncthreads();
    }
}

// ---------------- redo top-8 for flagged rows from exact q ----------------
__global__ void fixup_sel(const float* __restrict__ qfix, const float* __restrict__ kcm,
                          const float* __restrict__ kcx, const int* __restrict__ flags,
                          unsigned int* __restrict__ mask32) {
    int cnt = flags[0]; if (cnt > FLAGCAP) cnt = FLAGCAP;
    int i = blockIdx.x;
    if (i >= cnt) return;
    int e = flags[1 + i];
    int kv = e >> 16, qpos = e & 0xffff;
    int t = threadIdx.x;
    int c = t >> 3, g = t & 7;
    const float* qr = qfix + (size_t)i * 1024 + g * 128;
    const float* km = kcm + (kv * 16 + c) * 128;
    const float* kx = kcx + (kv * 16 + c) * 128;
    float dm = 0.f, dx = 0.f;
#pragma unroll 4
    for (int d = 0; d < 128; ++d) { float qv = qr[d]; dm += qv * km[d]; dx += qv * kx[d]; }
    float sg = (MIXLf * dm + (1.0f - MIXLf) * dx) * SCALEf;
    __shared__ float sh[16][8];
    __shared__ float vals[16];
    sh[c][g] = sg;
    __syncthreads();
    if (t < 16) {
        float mean = 0.f, mxv = -INFINITY;
#pragma unroll
        for (int gg = 0; gg < 8; ++gg) { mean += sh[t][gg]; mxv = fmaxf(mxv, sh[t][gg]); }
        mean *= 0.125f;
        float v = ALPHAf * mean + (1.0f - ALPHAf) * mxv;
        if (t * 128 > qpos) v = NEGf;
        vals[t] = v;
    }
    __syncthreads();
    if (t == 0) {
        unsigned int bits = 0;
        bool taken[16] = {};
        for (int it = 0; it < NBLK; ++it) {
            int best = 0; float bv = -INFINITY;
            for (int cc = 0; cc < 16; ++cc)
                if (!taken[cc] && vals[cc] > bv) { bv = vals[cc]; best = cc; }
            taken[best] = true;
            bits |= (1u << best);
        }
        int lastc = qpos >> 7;
        unsigned int causal_bits = (1u << (lastc + 1)) - 1u;
        mask32[kv * 2048 + qpos] = bits & causal_bits;
    }
}

// ---------------- MFMA flash attention (2-way chunk split per strip) ----------
// Block = 32 rows x head: 2 strips x 2 parity-waves. Each wave runs the R7
// body on chunks where rank%2==parity; partials merged per strip with exact
// online-softmax algebra (exp(m-M) scaling; empty partial -> scale 0).
// No barriers inside the chunk loop.
__global__ __launch_bounds__(256, 2) void attn_mfma(
        float* __restrict__ qbuf, const short* __restrict__ kb,
        const short* __restrict__ vtb, const unsigned int* __restrict__ mask32,
        const int* __restrict__ am, short* __restrict__ ab) {
    __shared__ short Psh[4][16][136];
    __shared__ float Mb[2][2][16];    // [strip][parity][row]
    __shared__ float Lb[2][2][16];
    __shared__ float Ob[2][8][16][17];
    const int tid = threadIdx.x;
    const int w = tid >> 6, lane = tid & 63;
    const int nl = lane & 15, quad = lane >> 4;
    const int h = blockIdx.y, kv = h >> 3;
    const int sIdx = w >> 1, par = w & 1;
    const int r0 = blockIdx.x * 32 + sIdx * 16;

    int qpos[4];
    unsigned rb[4];
#pragma unroll
    for (int r = 0; r < 4; ++r) {
        qpos[r] = r0 + quad * 4 + r;
        rb[r] = mask32[kv * Sn + qpos[r]];
    }
    unsigned bits = mask32[kv * Sn + r0 + nl];
#pragma unroll
    for (int off = 1; off < 64; off <<= 1) bits |= __shfl_xor(bits, off, 64);
    int wl = (r0 >= 15) ? ((r0 - 15) >> 7) : 0;
    int wh = (r0 + 15) >> 7;
    for (int c = wl; c <= wh; ++c) bits |= (1u << c);
    const int cmw = (r0 + 15) >> 7;
    bits &= (1u << (cmw + 1)) - 1u;

    short8 qf[4];
    const float* qrow = qbuf + (size_t)(r0 + nl) * 2048 + h * 128;
#pragma unroll
    for (int ks = 0; ks < 4; ++ks) {
        float4 a = *(const float4*)(qrow + ks * 32 + quad * 8);
        float4 b = *(const float4*)(qrow + ks * 32 + quad * 8 + 4);
        short8 v;
        v[0] = f2bf(a.x); v[1] = f2bf(a.y); v[2] = f2bf(a.z); v[3] = f2bf(a.w);
        v[4] = f2bf(b.x); v[5] = f2bf(b.y); v[6] = f2bf(b.z); v[7] = f2bf(b.w);
        qf[ks] = v;
    }

    f32x4 oacc[8];
#pragma unroll
    for (int dt = 0; dt < 8; ++dt) oacc[dt] = (f32x4){0.f, 0.f, 0.f, 0.f};
    float m[4] = {-INFINITY, -INFINITY, -INFINITY, -INFINITY};
    float l[4] = {0.f, 0.f, 0.f, 0.f};

    unsigned remb = bits;
    int ci = 0;
    while (remb) {
        const int c = __builtin_ctz(remb);
        remb &= remb - 1;
        if (((ci++) & 1) != par) continue;   // parity split of this strip's chunks
        const short* kcbase = kb + ((size_t)kv * Sn + c * 128) * 128;
        f32x4 sacc[8];
#pragma unroll
        for (int t = 0; t < 8; ++t) {
            const short* krow = kcbase + (t * 16 + nl) * 128;
            f32x4 a = (f32x4){0.f, 0.f, 0.f, 0.f};
#pragma unroll
            for (int ks = 0; ks < 4; ++ks) {
                short8 kf = *(const short8*)(krow + ks * 32 + quad * 8);
                a = __builtin_amdgcn_mfma_f32_16x16x32_bf16(qf[ks], kf, a, 0, 0, 0);
            }
            sacc[t] = a;
        }
        float cmax[4] = {-INFINITY, -INFINITY, -INFINITY, -INFINITY};
#pragma unroll
        for (int t = 0; t < 8; ++t) {
            int kp = c * 128 + t * 16 + nl;
            bool amok = am[kp] != 0;
#pragma unroll
            for (int r = 0; r < 4; ++r) {
                float s = sacc[t][r] * SCALEf;
                bool ok = (kp <= qpos[r]) && amok &&
                          (((rb[r] >> c) & 1u) || (qpos[r] - kp) < WINn);
                s = ok ? s : NEGf;
                sacc[t][r] = s;
                cmax[r] = fmaxf(cmax[r], s);
            }
        }
#pragma unroll
        for (int r = 0; r < 4; ++r)
#pragma unroll
            for (int off = 1; off < 16; off <<= 1)
                cmax[r] = fmaxf(cmax[r], __shfl_xor(cmax[r], off, 64));
        float fac[4], rsum[4];
#pragma unroll
        for (int r = 0; r < 4; ++r) {
            float newm = fmaxf(m[r], cmax[r]);
            fac[r] = __expf(m[r] - newm);
            m[r] = newm;
            rsum[r] = 0.f;
        }
#pragma unroll
        for (int t = 0; t < 8; ++t)
#pragma unroll
            for (int r = 0; r < 4; ++r) {
                float p = __expf(sacc[t][r] - m[r]);
                rsum[r] += p;
                Psh[w][quad * 4 + r][t * 16 + nl] = f2bf(p);
            }
#pragma unroll
        for (int r = 0; r < 4; ++r) {
#pragma unroll
            for (int off = 1; off < 16; off <<= 1)
                rsum[r] += __shfl_xor(rsum[r], off, 64);
            l[r] = l[r] * fac[r] + rsum[r];
        }
#pragma unroll
        for (int dt = 0; dt < 8; ++dt)
#pragma unroll
            for (int r = 0; r < 4; ++r) oacc[dt][r] *= fac[r];
        short8 pf[4];
        const short* prow = &Psh[w][nl][0];
#pragma unroll
        for (int ks = 0; ks < 4; ++ks) pf[ks] = *(const short8*)(prow + ks * 32 + quad * 8);
        const short* vcbase = vtb + (((size_t)kv * Ncn + c) * 128) * 128;
#pragma unroll
        for (int dt = 0; dt < 8; ++dt) {
            const short* vrow = vcbase + (dt * 16 + nl) * 128;
#pragma unroll
            for (int ks = 0; ks < 4; ++ks) {
                short8 vf = *(const short8*)(vrow + ks * 32 + quad * 8);
                oacc[dt] = __builtin_amdgcn_mfma_f32_16x16x32_bf16(pf[ks], vf, oacc[dt], 0, 0, 0);
            }
        }
    }
    // ---- merge the strip's 2 partials (exact online-softmax algebra) ----
    if (nl == 0) {
#pragma unroll
        for (int r = 0; r < 4; ++r) Mb[sIdx][par][quad * 4 + r] = m[r];
    }
    __syncthreads();
    float scale[4];
#pragma unroll
    for (int r = 0; r < 4; ++r) {
        int row = quad * 4 + r;
        float M = fmaxf(Mb[sIdx][0][row], Mb[sIdx][1][row]);
        scale[r] = __expf(m[r] - M);       // empty/garbage partial -> 0
    }
    if (nl == 0) {
#pragma unroll
        for (int r = 0; r < 4; ++r) Lb[sIdx][par][quad * 4 + r] = l[r] * scale[r];
    }
    if (par == 0) {
#pragma unroll
        for (int dt = 0; dt < 8; ++dt)
#pragma unroll
            for (int r = 0; r < 4; ++r)
                Ob[sIdx][dt][quad * 4 + r][nl] = oacc[dt][r] * scale[r];
    }
    __syncthreads();
    if (par == 1) {
#pragma unroll
        for (int dt = 0; dt < 8; ++dt)
#pragma unroll
            for (int r = 0; r < 4; ++r)
                Ob[sIdx][dt][quad * 4 + r][nl] += oacc[dt][r] * scale[r];
    }
    __syncthreads();
#pragma unroll
    for (int j = 0; j < 4; ++j) {
        int dt = par * 4 + j;
#pragma unroll
        for (int r = 0; r < 4; ++r) {
            int row = quad * 4 + r;
            float L = Lb[sIdx][0][row] + Lb[sIdx][1][row];
            float val = Ob[sIdx][dt][row][nl] / L;
            size_t off = (size_t)(r0 + row) * 2048 + h * 128 + dt * 16 + nl;
            qbuf[off] = val;
            ab[off] = f2bf(val);
        }
    }
}

extern "C" void kernel_launch(void* const* d_in, const int* in_sizes, int n_in,
                              void* d_out, int out_size, void* d_ws, size_t ws_size,
                              hipStream_t stream) {
    const float* hs   = (const float*)d_in[0];
    const float* cosb = (const float*)d_in[1];
    const float* sinb = (const float*)d_in[2];
    const int*   am   = (const int*)d_in[3];
    const float* Wq = (const float*)d_in[5];
    const float* bq = (const float*)d_in[6];
    const float* Wk = (const float*)d_in[7];
    const float* bk = (const float*)d_in[8];
    const float* Wv = (const float*)d_in[9];
    const float* bv = (const float*)d_in[10];
    const float* Wo = (const float*)d_in[11];
    float* out = (float*)d_out;

    float* qbuf = (float*)d_ws;                       // 4,194,304 f
    float* kbuf = qbuf + (size_t)Sn * HIDn;           // 524,288 f
    float* vbuf = kbuf + (size_t)Sn * HKVn * HDn;     // 524,288 f (fallback V / big-path WvT)
    float* kcm  = vbuf + (size_t)Sn * HKVn * HDn;     // 4096 f
    float* kcx  = kcm + 4096;                         // 4096 f
    unsigned int* mask32 = (unsigned int*)(kcx + 4096);  // 4096 u32
    int* flags = (int*)(mask32 + 4096);               // 4096 i32
    short* kb  = (short*)(flags + 4096);              // 524,288 s
    short* vtb = kb + (size_t)HKVn * Sn * HDn;        // 524,288 s
    char* P = (char*)(vtb + (size_t)HKVn * Sn * HDn);
    const size_t WSZ = (size_t)HIDn * HIDn * sizeof(short);   // 8,388,608 B
    size_t base = (size_t)((char*)P - (char*)d_ws);
    bool big = ws_size >= base + 2 * WSZ;

    dim3 blk(256);
    if (big) {
        short* W1 = (short*)P;              // Wq hi^T; later qfix; later Wo^T
        short* W2 = (short*)(P + WSZ);      // Wq lo^T; later ab
        short* ab = W2;
        float* qfix = (float*)W1;
        short* WvT = (short*)vbuf;          // 256*2048 s = 1 MB (vbuf unused on big path)
        trans_split<<<dim3(64, 64), blk, 0, stream>>>(Wq, W1, W2, HIDn, HIDn);
        gemm_mfma<1, false><<<dim3(16, 16), blk, 0, stream>>>(hs, W1, W2, bq, qbuf, nullptr, Sn, HIDn, HIDn);
        gemm64<<<dim3((HKVn * HDn) / 64, Sn / 64), blk, 0, stream>>>(hs, Wk, bk, kbuf, Sn, HKVn * HDn, HIDn);
        trans_split<<<dim3(8, 64), blk, 0, stream>>>(Wv, WvT, nullptr, HIDn, HKVn * HDn);
        gemm_mfma<2, true><<<dim3(2, 16), blk, 0, stream>>>(hs, WvT, nullptr, bv, nullptr, vtb, Sn, HKVn * HDn, HIDn);
        rope_kernel<<<(Sn * 18 * 64) / 256, blk, 0, stream>>>(qbuf, kbuf, cosb, sinb, kb);
        chunk_stats<<<HKVn * Ncn, 128, 0, stream>>>(kbuf, kcm, kcx, flags);
        block_scores<<<dim3(Sn, HKVn), 128, 0, stream>>>(qbuf, kcm, kcx, mask32, flags);
        fixup_q<<<2048, blk, 0, stream>>>(hs, Wq, bq, cosb, sinb, flags, qfix);
        fixup_sel<<<FLAGCAP, 128, 0, stream>>>(qfix, kcm, kcx, flags, mask32);
        attn_mfma<<<dim3(Sn / 32, HQn), blk, 0, stream>>>(qbuf, kb, vtb, mask32, am, ab);
        trans_split<<<dim3(64, 64), blk, 0, stream>>>(Wo, W1, nullptr, HIDn, HIDn);
        gemm_mfma<0, false><<<dim3(16, 16), blk, 0, stream>>>(ab, W1, nullptr, nullptr, out, nullptr, Sn, HIDn, HIDn);
    } else {
        short* ab = (short*)P;
        gemm64<<<dim3(HIDn / 64, Sn / 64), blk, 0, stream>>>(hs, Wq, bq, qbuf, Sn, HIDn, HIDn);
        gemm64<<<dim3((HKVn * HDn) / 64, Sn / 64), blk, 0, stream>>>(hs, Wk, bk, kbuf, Sn, HKVn * HDn, HIDn);
        gemm64<<<dim3((HKVn * HDn) / 64, Sn / 64), blk, 0, stream>>>(hs, Wv, bv, vbuf, Sn, HKVn * HDn, HIDn);
        rope_kernel<<<(Sn * 18 * 64) / 256, blk, 0, stream>>>(qbuf, kbuf, cosb, sinb, kb);
        conv_v<<<(Sn * 256) / 256, blk, 0, stream>>>(vbuf, vtb);
        chunk_stats<<<HKVn * Ncn, 128, 0, stream>>>(kbuf, kcm, kcx, flags);
        block_scores<<<dim3(Sn, HKVn), 128, 0, stream>>>(qbuf, kcm, kcx, mask32, flags);
        attn_mfma<<<dim3(Sn / 32, HQn), blk, 0, stream>>>(qbuf, kb, vtb, mask32, am, ab);
        gemm64<<<dim3(HIDn / 64, Sn / 64), blk, 0, stream>>>(qbuf, Wo, nullptr, out, Sn, HIDn, HIDn);
    }
}